// Round 2
// baseline (163.410 us; speedup 1.0000x reference)
//
#include <hip/hip_runtime.h>

// Problem constants (fixed by the reference)
#define NN 512
#define KK 17
#define WW 48
#define HH 64
#define HW (WW * HH)          // 3072 pixels per (n,k)
#define NQ 4                  // h-quarters per sample (occupancy: 2048 blocks)
#define RQ (HH / NQ)          // 16 rows per quarter
#define FQ (RQ * (WW / 4))    // 192 fv4 per quarter per item == threads/block
#define TPB FQ                // 192 threads = 3 waves
#define GRID (NN * NQ)        // 2048 blocks = 8 blocks/CU = 24 waves/CU

// Native clang vector type — required by __builtin_nontemporal_load
typedef float fv4 __attribute__((ext_vector_type(4)));

// Loss = mean over [N,K,H,W] of (w*(g - teacher))^2 with separable
// g = ex[w]*ey[h] and w = target_weight*mask. Stage ex (fv4) + the 16 ey
// rows of this block's h-quarter + w^2 in LDS, then stream the teacher
// slab with a 3-item-deep nontemporal register pipeline.
//
// vs round-0 version (512 blocks x 256 thr, 1-deep pipeline, ~8 waves/CU):
//  - 2048 blocks x 192 thr -> 24 waves/CU (3x TLP for latency hiding)
//  - 3 outstanding nt loads/thread (~73 KB in flight/CU, ~3x)
// Teacher reads stay NONTEMPORAL: the harness's 428 MB d_ws poison fill
// leaves the cache hierarchy full of dirty lines each timed iteration;
// nt streaming reads skip allocation so we don't force victim writebacks.

__global__ __launch_bounds__(TPB, 6) void reg2hm_partial_kernel(
    const float* __restrict__ pred,      // [N,K,2]
    const float* __restrict__ sigma,     // [N,K,2]
    const float* __restrict__ teacher,   // [N,K,H,W]
    const float* __restrict__ twgt,      // [N,K,1]
    float* __restrict__ ws)              // [GRID] partial sums
{
    __shared__ fv4   ex4[KK][WW / 4];    // 17 x 12 fv4 (all x for all items)
    __shared__ float eys[KK][RQ];        // 17 x 16 (only this quarter's rows)
    __shared__ float sw2[KK];            // (target_weight * mask)^2
    __shared__ float wave_sums[TPB / 64];

    const int b   = blockIdx.x;
    const int n   = b >> 2;              // sample
    const int q   = b & 3;               // h-quarter
    const int nk0 = n * KK;
    const int t   = threadIdx.x;

    // Per-item squared weight (mask * target_weight)^2
    if (t < KK) {
        const int nk = nk0 + t;
        const float mu_x = pred[nk * 2 + 0] * (float)WW;
        const float mu_y = pred[nk * 2 + 1] * (float)HH;
        const float sx   = sigma[nk * 2 + 0];
        const float sy   = sigma[nk * 2 + 1];
        const bool m = (mu_x - 3.0f * sx < (float)WW) &&
                       (mu_y - 3.0f * sy < (float)HH) &&
                       (mu_x + 3.0f * sx + 1.0f >= 0.0f) &&
                       (mu_y + 3.0f * sy + 1.0f >= 0.0f);
        const float w = twgt[nk] * (m ? 1.0f : 0.0f);
        sw2[t] = w * w;
    }

    // Stage separable exponentials: 17*(48+16) = 1088 entries.
    float* exf = (float*)ex4;
    for (int i = t; i < KK * (WW + RQ); i += TPB) {
        const int item = i / (WW + RQ);
        const int r    = i - item * (WW + RQ);
        const int nk   = nk0 + item;
        if (r < WW) {
            const float mu = pred[nk * 2 + 0] * (float)WW;
            const float s  = sigma[nk * 2 + 0];
            const float d  = (float)r - mu;
            exf[item * WW + r] = __expf(-d * d * (0.5f / (s * s + 1e-9f)));
        } else {
            const int h    = q * RQ + (r - WW);      // global row
            const float mu = pred[nk * 2 + 1] * (float)HH;
            const float s  = sigma[nk * 2 + 1];
            const float d  = (float)h - mu;
            eys[item][r - WW] = __expf(-d * d * (0.5f / (s * s + 1e-9f)));
        }
    }
    __syncthreads();

    // Thread t owns fv4 index t of this quarter: row = t/12, slot = t%12.
    const int hl = t / 12;               // 0..15 (local row)
    const int s  = t - hl * 12;          // 0..11 (fv4 slot in row)

    // Quarter slab is contiguous: item*768 + q*192 + t  (fv4 units)
    const fv4* tp = (const fv4*)teacher + (size_t)nk0 * (HW / 4) + q * FQ + t;

    // 3-deep software pipeline over the 17 items, 1 fv4/item/thread,
    // all teacher reads nontemporal (streaming, no cache allocation).
    fv4 c0 = __builtin_nontemporal_load(tp + 0 * (HW / 4));
    fv4 c1 = __builtin_nontemporal_load(tp + 1 * (HW / 4));
    fv4 c2 = __builtin_nontemporal_load(tp + 2 * (HW / 4));
    float total = 0.0f;
#pragma unroll 1
    for (int item = 0; item < KK; ++item) {
        fv4 nx = c2;                     // harmless filler on drain iterations
        if (item + 3 < KK)
            nx = __builtin_nontemporal_load(tp + (item + 3) * (HW / 4));
        const fv4   e = ex4[item][s];
        const float y = eys[item][hl];
        const fv4   d = e * y - c0;
        total += sw2[item] * (d.x * d.x + d.y * d.y + d.z * d.z + d.w * d.w);
        c0 = c1; c1 = c2; c2 = nx;
    }

    // Wave(64) shuffle reduction, then cross-wave via LDS.
#pragma unroll
    for (int off = 32; off > 0; off >>= 1)
        total += __shfl_down(total, off, 64);

    const int wave = t >> 6;
    const int lane = t & 63;
    if (lane == 0) wave_sums[wave] = total;
    __syncthreads();

    if (t == 0)
        ws[b] = wave_sums[0] + wave_sums[1] + wave_sums[2];
}

__global__ __launch_bounds__(256) void reg2hm_final_kernel(
    const float* __restrict__ ws, float* __restrict__ out)
{
    __shared__ float wave_sums[4];
    const int t = threadIdx.x;
    float sum = 0.0f;
    for (int i = t; i < GRID; i += 256) sum += ws[i];
#pragma unroll
    for (int off = 32; off > 0; off >>= 1)
        sum += __shfl_down(sum, off, 64);
    const int wave = t >> 6;
    const int lane = t & 63;
    if (lane == 0) wave_sums[wave] = sum;
    __syncthreads();
    if (t == 0) {
        const float total = wave_sums[0] + wave_sums[1] + wave_sums[2] + wave_sums[3];
        out[0] = total * (1.0f / ((float)NN * KK * HW));
    }
}

extern "C" void kernel_launch(void* const* d_in, const int* in_sizes, int n_in,
                              void* d_out, int out_size, void* d_ws, size_t ws_size,
                              hipStream_t stream) {
    const float* pred    = (const float*)d_in[0];
    const float* sigma   = (const float*)d_in[1];
    const float* teacher = (const float*)d_in[2];
    const float* twgt    = (const float*)d_in[3];
    float* out = (float*)d_out;
    float* ws  = (float*)d_ws;   // needs GRID*4 = 8192 bytes

    reg2hm_partial_kernel<<<GRID, TPB, 0, stream>>>(pred, sigma, teacher, twgt, ws);
    reg2hm_final_kernel<<<1, 256, 0, stream>>>(ws, out);
}